// Round 9
// baseline (64.157 us; speedup 1.0000x reference)
//
#include <hip/hip_runtime.h>

#define ALPHA_C    0.5f
#define C_CLASSES  100000
#define D          128
#define BATCH      131072
#define CHUNK      2048
#define NB         ((C_CLASSES + CHUNK - 1) / CHUNK)   // 49 scan blocks

// ---------------------------------------------------------------------------
// DPP 32-lane group reduce (VALU-speed). row_shr 1,2,4,8 then bcast15:
// lane 31 = sum of lanes 0..31, lane 63 = sum of lanes 32..63.
// ---------------------------------------------------------------------------
template<int CTRL, int RMASK>
__device__ __forceinline__ float dpp_add(float x) {
    int v = __builtin_amdgcn_update_dpp(0, __float_as_int(x), CTRL, RMASK, 0xF, true);
    return x + __int_as_float(v);
}
__device__ __forceinline__ float group_sum(float ss) {
    ss = dpp_add<0x111, 0xF>(ss);   // row_shr:1
    ss = dpp_add<0x112, 0xF>(ss);   // row_shr:2
    ss = dpp_add<0x114, 0xF>(ss);   // row_shr:4
    ss = dpp_add<0x118, 0xF>(ss);   // row_shr:8
    ss = dpp_add<0x142, 0xA>(ss);   // row_bcast15 -> rows 1,3
    return ss;                      // lane31 / lane63 hold the 32-lane sums
}

// ---------------------------------------------------------------------------
// K1: label histogram
// ---------------------------------------------------------------------------
__global__ void hist_kernel(const int* __restrict__ labels,
                            int* __restrict__ counts) {
    int i = blockIdx.x * blockDim.x + threadIdx.x;   // grid == BATCH exactly
    atomicAdd(&counts[labels[i]], 1);
}

// ---------------------------------------------------------------------------
// K2: per-chunk exclusive scan of counts; writes {chunk_excl, count} pairs
// ---------------------------------------------------------------------------
__global__ __launch_bounds__(256)
void scan1_kernel(const int* __restrict__ counts,
                  int2* __restrict__ co,
                  int* __restrict__ blockSums) {
    __shared__ int sdata[256];
    const int tid  = threadIdx.x;
    const int base = blockIdx.x * CHUNK + tid * 8;
    int v[8]; int s = 0;
    #pragma unroll
    for (int j = 0; j < 8; ++j) {
        int idx = base + j;
        v[j] = (idx < C_CLASSES) ? counts[idx] : 0;
        s += v[j];
    }
    sdata[tid] = s;
    __syncthreads();
    #pragma unroll
    for (int off = 1; off < 256; off <<= 1) {
        int t = (tid >= off) ? sdata[tid - off] : 0;
        __syncthreads();
        sdata[tid] += t;
        __syncthreads();
    }
    int excl = sdata[tid] - s;
    #pragma unroll
    for (int j = 0; j < 8; ++j) {
        int idx = base + j;
        if (idx < C_CLASSES) co[idx] = make_int2(excl, v[j]);
        excl += v[j];
    }
    if (tid == 255) blockSums[blockIdx.x] = sdata[255];
}

// ---------------------------------------------------------------------------
// K3: single-wave scan of the 49 chunk totals
// ---------------------------------------------------------------------------
__global__ void scan2_kernel(const int* __restrict__ blockSums,
                             int* __restrict__ blockOffsets) {
    const int lane = threadIdx.x;
    int v = (lane < NB) ? blockSums[lane] : 0;
    int incl = v;
    #pragma unroll
    for (int off = 1; off < 64; off <<= 1) {
        int t = __shfl_up(incl, off);
        if (lane >= off) incl += t;
    }
    blockOffsets[lane] = incl - v;
}

// ---------------------------------------------------------------------------
// K4: finalize offsets in co.x; seed scatter cursor
// ---------------------------------------------------------------------------
__global__ void addoff_kernel(int2* __restrict__ co,
                              const int* __restrict__ blockOffsets,
                              int* __restrict__ cursor) {
    int i = blockIdx.x * blockDim.x + threadIdx.x;
    if (i < C_CLASSES) {
        int f = co[i].x + blockOffsets[i / CHUNK];
        co[i].x = f;
        cursor[i] = f;
    }
}

// ---------------------------------------------------------------------------
// K5: scatter sample indices into class buckets
// ---------------------------------------------------------------------------
__global__ void scatter_kernel(const int* __restrict__ labels,
                               int* __restrict__ cursor,
                               int* __restrict__ order) {
    int b = blockIdx.x * blockDim.x + threadIdx.x;   // grid == BATCH exactly
    int pos = atomicAdd(&cursor[labels[b]], 1);
    order[pos] = b;
}

// ---------------------------------------------------------------------------
// K5b: pack {start, n, b0, b1} per class. Removes the order-load hop from
// the fused kernel's dependent chain for n<=2 classes (85%).
// order[] is fully written before this runs; clamps keep reads in-range
// (n==0/1 classes read a neighbor's sample index but never use it).
// ---------------------------------------------------------------------------
__global__ void meta_kernel(const int2* __restrict__ co,
                            const int*  __restrict__ order,
                            int4* __restrict__ meta) {
    int i = blockIdx.x * blockDim.x + threadIdx.x;
    if (i < C_CLASSES) {
        const int2 m = co[i];
        const int b0 = order[min(m.x,     BATCH - 1)];
        const int b1 = order[min(m.x + 1, BATCH - 1)];
        meta[i] = make_int4(m.x, m.y, b0, b1);
    }
}

// ---------------------------------------------------------------------------
// K6 (R9): dim-major fused kernel, chain-shortened.
//   hop 1: meta[c] (one dwordx4)  ->  hop 2: features[b0], features[b1]
//   (parallel, exec-mask predicated so n<2 classes add no traffic).
//   n>=3 remainder unrolled by 2: both order loads issue together, then
//   both feature rows together -> 2 hops per 2 samples (was 2 per sample).
// ---------------------------------------------------------------------------
__global__ __launch_bounds__(256)
void fused_kernel(const float* __restrict__ features,
                  const float* __restrict__ centers,
                  const int4*  __restrict__ meta,
                  const int*   __restrict__ order,
                  float* __restrict__ result,
                  float* __restrict__ out_centers) {
    const int wave = threadIdx.x >> 6;
    const int lane = threadIdx.x & 63;
    const int t    = lane & 31;                       // dim-quad index
    const int c    = (blockIdx.x * 4 + wave) * 2 + (lane >> 5);  // grid exact

    const int4 m    = meta[c];                        // hop 1
    const int start = m.x;
    const int n     = m.y;

    const float4 cv = ((const float4*)(centers + (size_t)c * D))[t];

    float ax = 0.f, ay = 0.f, az = 0.f, aw = 0.f;

    // first two samples: indices came with meta -> feature loads are hop 2,
    // issue in parallel. Predicated so n==0/1 classes skip the traffic.
    float4 f0 = make_float4(0.f, 0.f, 0.f, 0.f);
    float4 f1 = make_float4(0.f, 0.f, 0.f, 0.f);
    if (n >= 1) f0 = ((const float4*)(features + (size_t)m.z * D))[t];
    if (n >= 2) f1 = ((const float4*)(features + (size_t)m.w * D))[t];

    if (n >= 1) {
        const float dx = f0.x - cv.x, dy = f0.y - cv.y;
        const float dz = f0.z - cv.z, dw = f0.w - cv.w;
        ax += dx; ay += dy; az += dz; aw += dw;
        const float ss = group_sum(dx * dx + dy * dy + dz * dz + dw * dw);
        if (t == 31) result[m.z] = ss;
    }
    if (n >= 2) {
        const float dx = f1.x - cv.x, dy = f1.y - cv.y;
        const float dz = f1.z - cv.z, dw = f1.w - cv.w;
        ax += dx; ay += dy; az += dz; aw += dw;
        const float ss = group_sum(dx * dx + dy * dy + dz * dz + dw * dw);
        if (t == 31) result[m.w] = ss;
    }

    // remainder (15% of classes), 2 samples per round: order loads paired,
    // feature loads paired -> 2 latency hops per 2 samples.
    for (int j = 2; j < n; j += 2) {
        const bool hasB = (j + 1) < n;
        const int bA = order[start + j];
        const int bB = order[min(start + j + 1, BATCH - 1)];
        const float4 fA = ((const float4*)(features + (size_t)bA * D))[t];
        float4 fB = make_float4(0.f, 0.f, 0.f, 0.f);
        if (hasB) fB = ((const float4*)(features + (size_t)bB * D))[t];

        {
            const float dx = fA.x - cv.x, dy = fA.y - cv.y;
            const float dz = fA.z - cv.z, dw = fA.w - cv.w;
            ax += dx; ay += dy; az += dz; aw += dw;
            const float ss = group_sum(dx * dx + dy * dy + dz * dz + dw * dw);
            if (t == 31) result[bA] = ss;
        }
        if (hasB) {
            const float dx = fB.x - cv.x, dy = fB.y - cv.y;
            const float dz = fB.z - cv.z, dw = fB.w - cv.w;
            ax += dx; ay += dy; az += dz; aw += dw;
            const float ss = group_sum(dx * dx + dy * dy + dz * dz + dw * dw);
            if (t == 31) result[bB] = ss;
        }
    }

    const float inv = ALPHA_C / (1.0f + (float)n);
    float4 o;
    o.x = cv.x + ax * inv;
    o.y = cv.y + ay * inv;
    o.z = cv.z + az * inv;
    o.w = cv.w + aw * inv;
    ((float4*)(out_centers + (size_t)c * D))[t] = o;
}

// ---------------------------------------------------------------------------
extern "C" void kernel_launch(void* const* d_in, const int* in_sizes, int n_in,
                              void* d_out, int out_size, void* d_ws, size_t ws_size,
                              hipStream_t stream) {
    const float* features = (const float*)d_in[0];
    const int*   labels   = (const int*)d_in[1];
    const float* centers  = (const float*)d_in[2];

    float* result      = (float*)d_out;          // [BATCH]
    float* out_centers = result + BATCH;         // [C_CLASSES * D]

    // ws layout (ints): counts/cursor aliased (counts dead after scan1,
    // cursor written in addoff afterwards) -> saves C ints.
    int*  ws           = (int*)d_ws;
    int*  counts       = ws;                         // [0, C)      (later: cursor)
    int*  cursor       = ws;                         // alias of counts
    int2* co           = (int2*)(ws + C_CLASSES);    // [C, 3C)
    int4* meta         = (int4*)(ws + 3 * C_CLASSES);// [3C, 7C)  16B-aligned
    int*  blockSums    = ws + 7 * C_CLASSES;         // 64
    int*  blockOffsets = blockSums + 64;             // 64
    int*  order        = blockOffsets + 64;          // BATCH

    (void)hipMemsetAsync(counts, 0, C_CLASSES * sizeof(int), stream);

    hist_kernel   <<<BATCH / 256, 256, 0, stream>>>(labels, counts);
    scan1_kernel  <<<NB,          256, 0, stream>>>(counts, co, blockSums);
    scan2_kernel  <<<1,            64, 0, stream>>>(blockSums, blockOffsets);
    addoff_kernel <<<(C_CLASSES + 255) / 256, 256, 0, stream>>>(co, blockOffsets, cursor);
    scatter_kernel<<<BATCH / 256, 256, 0, stream>>>(labels, cursor, order);
    meta_kernel   <<<(C_CLASSES + 255) / 256, 256, 0, stream>>>(co, order, meta);

    fused_kernel  <<<C_CLASSES / 8, 256, 0, stream>>>(
        features, centers, meta, order, result, out_centers);
}